// Round 1
// baseline (2065.252 us; speedup 1.0000x reference)
//
#include <hip/hip_runtime.h>
#include <cstdint>

#define NM 20   // MAX_OBJECTS
#define ND 16   // NODE_DIM
#define HD 64   // HIDDEN

// ---- transposed-weight static device buffer (written by prep kernel every launch) ----
#define OFF_NE    0         // 16 x 64   : neT[k*64+o]   = ne_w[o*16+k]
#define OFF_M1W1  1024      // 128 x 64  : w1T[k*64+o]   = mp1_w1[o*128+k]
#define OFF_M1W2  9216      // 64 x 64
#define OFF_M2W1  13312     // 128 x 64
#define OFF_M2W2  21504     // 64 x 64
#define OFF_WIH   25600     // 72 x 192  : wihT[k*192+r] = gru_wih[r*72+k]
#define OFF_WHH   39424     // 64 x 192
#define OFF_PQ    51712     // 64 x 64
#define OFF_PACK  55808     // 64 x 28   : [k*28 + l] l: 0..7 op, 8..17 c1, 18..27 c2
#define WT_TOTAL  57600

__device__ float g_wT[WT_TOTAL];

__device__ __forceinline__ float rl(float v, int k) {
  return __int_as_float(__builtin_amdgcn_readlane(__float_as_int(v), k));
}

__device__ __forceinline__ float wsum64(float v) {
  v += __shfl_xor(v, 1, 64);
  v += __shfl_xor(v, 2, 64);
  v += __shfl_xor(v, 4, 64);
  v += __shfl_xor(v, 8, 64);
  v += __shfl_xor(v, 16, 64);
  v += __shfl_xor(v, 32, 64);
  return v;
}

// acc[n] += sum_k rl(x[n],k) * wT[k*64 + o],  k < 64
#define GEMV20(XARR, ACC, WTP)                               \
  { const float* _p = (WTP) + o;                             \
    _Pragma("unroll 4")                                      \
    for (int _k = 0; _k < HD; _k++) {                        \
      float _w = _p[_k * HD];                                \
      _Pragma("unroll")                                      \
      for (int _n = 0; _n < NM; _n++)                        \
        ACC[_n] = fmaf(rl(XARR[_n], _k), _w, ACC[_n]);       \
    } }

// acc += sum_k rl(x,k) * wT[k*64 + o]
#define GEMV1(XS, ACC, WTP)                                  \
  { const float* _p = (WTP) + o;                             \
    _Pragma("unroll 8")                                      \
    for (int _k = 0; _k < HD; _k++)                          \
      ACC = fmaf(rl(XS, _k), _p[_k * HD], ACC);              \
  }

__global__ void prep_transpose(const float* __restrict__ ne_w,
                               const float* __restrict__ m1w1, const float* __restrict__ m1w2,
                               const float* __restrict__ m2w1, const float* __restrict__ m2w2,
                               const float* __restrict__ wih,  const float* __restrict__ whh,
                               const float* __restrict__ pqw,  const float* __restrict__ opw,
                               const float* __restrict__ c1w,  const float* __restrict__ c2w)
{
  const int t = blockIdx.x * blockDim.x + threadIdx.x;
  const int T = gridDim.x * blockDim.x;
  for (int i = t; i < 64*16;  i += T) { int o_ = i >> 4, k = i & 15;  g_wT[OFF_NE   + k*64  + o_] = ne_w[i]; }
  for (int i = t; i < 64*128; i += T) { int o_ = i >> 7, k = i & 127; g_wT[OFF_M1W1 + k*64  + o_] = m1w1[i]; }
  for (int i = t; i < 64*64;  i += T) { int o_ = i >> 6, k = i & 63;  g_wT[OFF_M1W2 + k*64  + o_] = m1w2[i]; }
  for (int i = t; i < 64*128; i += T) { int o_ = i >> 7, k = i & 127; g_wT[OFF_M2W1 + k*64  + o_] = m2w1[i]; }
  for (int i = t; i < 64*64;  i += T) { int o_ = i >> 6, k = i & 63;  g_wT[OFF_M2W2 + k*64  + o_] = m2w2[i]; }
  for (int i = t; i < 192*72; i += T) { int r  = i / 72, k = i % 72;  g_wT[OFF_WIH  + k*192 + r ] = wih[i]; }
  for (int i = t; i < 192*64; i += T) { int r  = i >> 6, k = i & 63;  g_wT[OFF_WHH  + k*192 + r ] = whh[i]; }
  for (int i = t; i < 64*64;  i += T) { int o_ = i >> 6, k = i & 63;  g_wT[OFF_PQ   + k*64  + o_] = pqw[i]; }
  for (int i = t; i < 8*64;   i += T) { int l  = i >> 6, k = i & 63;  g_wT[OFF_PACK + k*28  + l ] = opw[i]; }
  for (int i = t; i < 10*64;  i += T) { int l  = i >> 6, k = i & 63;  g_wT[OFF_PACK + k*28 + 8  + l] = c1w[i]; }
  for (int i = t; i < 10*64;  i += T) { int l  = i >> 6, k = i & 63;  g_wT[OFF_PACK + k*28 + 18 + l] = c2w[i]; }
}

__global__ void __launch_bounds__(256)
msp_main(const float* __restrict__ nf, const int* __restrict__ nnp,
         const float* __restrict__ rnn, const float* __restrict__ poh,
         const float* __restrict__ ne_b,
         const float* __restrict__ m1b1, const float* __restrict__ m1b2,
         const float* __restrict__ n1g, const float* __restrict__ n1b,
         const float* __restrict__ m2b1, const float* __restrict__ m2b2,
         const float* __restrict__ n2g, const float* __restrict__ n2b,
         const float* __restrict__ bih, const float* __restrict__ bhh,
         const float* __restrict__ opb, const float* __restrict__ c1b,
         const float* __restrict__ c2b, const float* __restrict__ pqb,
         const float* __restrict__ pkw, const float* __restrict__ pkb,
         float* __restrict__ out, int B)
{
  const int lane = threadIdx.x & 63;
  int b0 = blockIdx.x * 4 + (threadIdx.x >> 6);
  if (b0 >= B) return;
  const int b = __builtin_amdgcn_readfirstlane(b0);   // wave-uniform -> scalarize addresses
  const int o = lane;
  const int nn = __builtin_amdgcn_readfirstlane(nnp[b]);  // 1..20
  const float inv_nn = 1.0f / (float)nn;

  // ---------------- encode: h[n][o] = ne_b[o] + sum_k nf[b,n,k]*ne_w[o,k] ----------------
  float h[NM];
  {
    const float* nfb = nf + (size_t)b * (NM * ND);
    const float bo = ne_b[o];
    float wv[ND];
    #pragma unroll
    for (int k = 0; k < ND; k++) wv[k] = g_wT[OFF_NE + k * HD + o];
    #pragma unroll
    for (int n = 0; n < NM; n++) {
      float a = bo;
      #pragma unroll
      for (int k = 0; k < ND; k++) a = fmaf(nfb[n * ND + k], wv[k], a);  // uniform -> s_load
      h[n] = a;
    }
  }

  // ---------------- MP block 1 ----------------
  float msg = 0.0f;
  #pragma unroll
  for (int n = 0; n < NM; n++) msg += (n < nn) ? h[n] : 0.0f;
  msg *= inv_nn;

  float t[NM];
  {
    float cm = m1b1[o];
    GEMV1(msg, cm, g_wT + OFF_M1W1 + 64 * HD);       // msg part of concat (cols 64..127)
    #pragma unroll
    for (int n = 0; n < NM; n++) t[n] = cm;
    GEMV20(h, t, g_wT + OFF_M1W1);                   // h part (cols 0..63)
    #pragma unroll
    for (int n = 0; n < NM; n++) t[n] = fmaxf(t[n], 0.0f);
    const float b2 = m1b2[o];
    #pragma unroll
    for (int n = 0; n < NM; n++) h[n] += b2;         // residual + bias2
    GEMV20(t, h, g_wT + OFF_M1W2);
  }
  {
    const float g = n1g[o], be = n1b[o];
    #pragma unroll
    for (int n = 0; n < NM; n++) {
      float mu  = wsum64(h[n]) * 0.015625f;
      float d   = h[n] - mu;
      float var = wsum64(d * d) * 0.015625f;
      float y   = fmaf(d * (1.0f / sqrtf(var + 1e-5f)), g, 0.0f) + be;
      h[n] = (n < nn) ? y : 0.0f;                    // * mf
    }
  }

  // ---------------- MP block 2 ----------------
  msg = 0.0f;
  #pragma unroll
  for (int n = 0; n < NM; n++) msg += (n < nn) ? h[n] : 0.0f;
  msg *= inv_nn;
  {
    float cm = m2b1[o];
    GEMV1(msg, cm, g_wT + OFF_M2W1 + 64 * HD);
    #pragma unroll
    for (int n = 0; n < NM; n++) t[n] = cm;
    GEMV20(h, t, g_wT + OFF_M2W1);
    #pragma unroll
    for (int n = 0; n < NM; n++) t[n] = fmaxf(t[n], 0.0f);
    const float b2 = m2b2[o];
    #pragma unroll
    for (int n = 0; n < NM; n++) h[n] += b2;
    GEMV20(t, h, g_wT + OFF_M2W2);
  }
  {
    const float g = n2g[o], be = n2b[o];
    #pragma unroll
    for (int n = 0; n < NM; n++) {
      float mu  = wsum64(h[n]) * 0.015625f;
      float d   = h[n] - mu;
      float var = wsum64(d * d) * 0.015625f;
      float y   = fmaf(d * (1.0f / sqrtf(var + 1e-5f)), g, 0.0f) + be;
      h[n] = (n < nn) ? y : 0.0f;
    }
  }

  // ---------------- graph_vec + GRU ----------------
  float gv = 0.0f;
  #pragma unroll
  for (int n = 0; n < NM; n++) gv += (n < nn) ? h[n] : 0.0f;
  gv *= inv_nn;

  const float st = rnn[(size_t)b * HD + o];
  float gi0 = bih[o], gi1 = bih[64 + o], gi2 = bih[128 + o];
  {
    const float* p = g_wT + OFF_WIH + o;
    #pragma unroll 4
    for (int k = 0; k < 64; k++) {
      float x = rl(gv, k);
      gi0 = fmaf(x, p[k * 192      ], gi0);
      gi1 = fmaf(x, p[k * 192 +  64], gi1);
      gi2 = fmaf(x, p[k * 192 + 128], gi2);
    }
    const float* pohb = poh + (size_t)b * 8;         // uniform -> scalar loads
    #pragma unroll
    for (int k = 0; k < 8; k++) {
      float x = pohb[k];
      gi0 = fmaf(x, p[(64 + k) * 192      ], gi0);
      gi1 = fmaf(x, p[(64 + k) * 192 +  64], gi1);
      gi2 = fmaf(x, p[(64 + k) * 192 + 128], gi2);
    }
  }
  float gh0 = bhh[o], gh1 = bhh[64 + o], gh2 = bhh[128 + o];
  {
    const float* p = g_wT + OFF_WHH + o;
    #pragma unroll 4
    for (int k = 0; k < 64; k++) {
      float x = rl(st, k);
      gh0 = fmaf(x, p[k * 192      ], gh0);
      gh1 = fmaf(x, p[k * 192 +  64], gh1);
      gh2 = fmaf(x, p[k * 192 + 128], gh2);
    }
  }
  const float rg = 1.0f / (1.0f + expf(-(gi0 + gh0)));
  const float zg = 1.0f / (1.0f + expf(-(gi1 + gh1)));
  const float ng = tanhf(fmaf(rg, gh2, gi2));
  const float ns = (1.0f - zg) * ng + zg * st;       // new_state[o]

  // ---------------- heads ----------------
  out[(size_t)B * 48 + (size_t)b * HD + o] = ns;     // new_state

  float q = pqb[o];
  GEMV1(ns, q, g_wT + OFF_PQ);                       // query[o]

  {                                                  // packed op/c1/c2 logits
    float a;
    if      (lane < 8)  a = opb[lane];
    else if (lane < 18) a = c1b[lane - 8];
    else if (lane < 28) a = c2b[lane - 18];
    else                a = 0.0f;
    const float* p = g_wT + OFF_PACK + ((lane < 28) ? lane : 0);
    #pragma unroll 8
    for (int k = 0; k < 64; k++)
      a = fmaf(rl(ns, k), p[k * 28], a);
    if      (lane < 8)  out[(size_t)b * 8 + lane] = a;
    else if (lane < 18) out[(size_t)B * 8  + (size_t)b * 10 + (lane - 8)]  = a;
    else if (lane < 28) out[(size_t)B * 18 + (size_t)b * 10 + (lane - 18)] = a;
  }

  // pointer: ptr[n] = q.pk_b + sum_k h2[n][k] * (pk_w^T q)[k]
  float qw = 0.0f;
  {
    const float* p = pkw + lane;                     // pk_w[oo*64 + lane], coalesced per oo
    #pragma unroll 4
    for (int oo = 0; oo < 64; oo++)
      qw = fmaf(rl(q, oo), p[oo * 64], qw);
  }
  const float qbd = wsum64(q * pkb[lane]);

  float myp = 0.0f;
  #pragma unroll
  for (int n = 0; n < NM; n++) {
    float s = wsum64(h[n] * qw) + qbd;
    if (lane == n) myp = s;
  }
  if (lane < NM)
    out[(size_t)B * 28 + (size_t)b * NM + lane] = (lane < nn) ? myp : -1e9f;
}

extern "C" void kernel_launch(void* const* d_in, const int* in_sizes, int n_in,
                              void* d_out, int out_size, void* d_ws, size_t ws_size,
                              hipStream_t stream)
{
  (void)n_in; (void)out_size; (void)d_ws; (void)ws_size;
  const float* nf   = (const float*)d_in[0];
  const int*   nnp  = (const int*)  d_in[1];
  const float* rnn  = (const float*)d_in[2];
  const float* poh  = (const float*)d_in[3];
  const float* ne_w = (const float*)d_in[4];
  const float* ne_b = (const float*)d_in[5];
  const float* m1w1 = (const float*)d_in[6];
  const float* m1b1 = (const float*)d_in[7];
  const float* m1w2 = (const float*)d_in[8];
  const float* m1b2 = (const float*)d_in[9];
  const float* n1g  = (const float*)d_in[10];
  const float* n1b  = (const float*)d_in[11];
  const float* m2w1 = (const float*)d_in[12];
  const float* m2b1 = (const float*)d_in[13];
  const float* m2w2 = (const float*)d_in[14];
  const float* m2b2 = (const float*)d_in[15];
  const float* n2g  = (const float*)d_in[16];
  const float* n2b  = (const float*)d_in[17];
  const float* wih  = (const float*)d_in[18];
  const float* whh  = (const float*)d_in[19];
  const float* bih  = (const float*)d_in[20];
  const float* bhh  = (const float*)d_in[21];
  const float* opw  = (const float*)d_in[22];
  const float* opb  = (const float*)d_in[23];
  const float* c1w  = (const float*)d_in[24];
  const float* c1b  = (const float*)d_in[25];
  const float* c2w  = (const float*)d_in[26];
  const float* c2b  = (const float*)d_in[27];
  const float* pqw  = (const float*)d_in[28];
  const float* pqb  = (const float*)d_in[29];
  const float* pkw  = (const float*)d_in[30];
  const float* pkb  = (const float*)d_in[31];
  float* out = (float*)d_out;
  const int B = in_sizes[1];   // n_nodes has B elements

  prep_transpose<<<64, 256, 0, stream>>>(ne_w, m1w1, m1w2, m2w1, m2w2,
                                         wih, whh, pqw, opw, c1w, c2w);
  msp_main<<<(B + 3) / 4, 256, 0, stream>>>(nf, nnp, rnn, poh, ne_b,
                                            m1b1, m1b2, n1g, n1b,
                                            m2b1, m2b2, n2g, n2b,
                                            bih, bhh, opb, c1b, c2b,
                                            pqb, pkw, pkb, out, B);
}

// Round 3
// 667.213 us; speedup vs baseline: 3.0953x; 3.0953x over previous
//
#include <hip/hip_runtime.h>
#include <cstdint>

#define NM 20
#define HS 72          // hbuf row stride in bf16 elements (144 B, 16B-aligned)

typedef __attribute__((ext_vector_type(8))) short bf16x8;
typedef __attribute__((ext_vector_type(4))) float f32x4;

#define MFMA(A, Bf, C) __builtin_amdgcn_mfma_f32_16x16x32_bf16((A), (Bf), (C), 0, 0, 0)

// ---- fragment-packed weights (bf16), built by prep kernel every launch ----
// frag f = (chunk*NBLK + nb); element addr = OFS + f*512 + lane*8 + j
#define F_NE    0        // 1c x 4nb   (K=16 pad 32, N=64)
#define F_M1W1  2048     // 4c x 4nb   (K=128, N=64)
#define F_M1W2  10240    // 2c x 4nb
#define F_M2W1  14336    // 4c x 4nb
#define F_M2W2  22528    // 2c x 4nb
#define F_WIH   26624    // 3c x 12nb  (K=72 pad 96, N=192)
#define F_WHH   45056    // 2c x 12nb  (K=64, N=192)
#define F_PQ    57344    // 2c x 4nb
#define F_PACK  61440    // 2c x 2nb   (K=64, N=28 pad 32: op|c1|c2)
#define F_PK    63488    // 2c x 4nb
#define F_TOTAL 67584

__device__ __align__(16) short g_fr[F_TOTAL];

__device__ __forceinline__ short bf16rn(float x) {
  unsigned u = __float_as_uint(x);
  u += 0x7fffu + ((u >> 16) & 1u);
  return (short)(u >> 16);
}
__device__ __forceinline__ float bf2f(short s) {
  return __uint_as_float(((unsigned)(unsigned short)s) << 16);
}

#define LDF(off) (*(const bf16x8*)(g_fr + (off) + lane * 8))

// ---------------- prep: pack weights into B-fragment lane order ----------------
// B[k][n] = W[n][k]; lane l holds col n = nb*16 + (l&15), k = c*32 + (l>>4)*8 + j
#define BUILD(OFS, CH, NBL, GETEXPR)                                   \
  for (int i = t; i < (CH) * (NBL) * 512; i += T) {                    \
    int j = i & 7, ln = (i >> 3) & 63, f = i >> 9;                     \
    int c = f / (NBL), nb = f % (NBL);                                 \
    int k = c * 32 + ((ln >> 4)) * 8 + j;                              \
    int n = nb * 16 + (ln & 15);                                       \
    (void)c; (void)k; (void)n;                                         \
    g_fr[(OFS) + i] = bf16rn(GETEXPR);                                 \
  }

__global__ void __launch_bounds__(256)
prep_frag(const float* __restrict__ ne_w,
          const float* __restrict__ m1w1, const float* __restrict__ m1w2,
          const float* __restrict__ m2w1, const float* __restrict__ m2w2,
          const float* __restrict__ wih,  const float* __restrict__ whh,
          const float* __restrict__ pqw,  const float* __restrict__ opw,
          const float* __restrict__ c1w,  const float* __restrict__ c2w,
          const float* __restrict__ pkw)
{
  const int t = blockIdx.x * blockDim.x + threadIdx.x;
  const int T = gridDim.x * blockDim.x;
  BUILD(F_NE,   1, 4,  (k < 16 ? ne_w[n * 16 + k] : 0.f))
  BUILD(F_M1W1, 4, 4,  m1w1[n * 128 + k])
  BUILD(F_M1W2, 2, 4,  m1w2[n * 64 + k])
  BUILD(F_M2W1, 4, 4,  m2w1[n * 128 + k])
  BUILD(F_M2W2, 2, 4,  m2w2[n * 64 + k])
  BUILD(F_WIH,  3, 12, (k < 72 ? wih[n * 72 + k] : 0.f))
  BUILD(F_WHH,  2, 12, whh[n * 64 + k])
  BUILD(F_PQ,   2, 4,  pqw[n * 64 + k])
  BUILD(F_PACK, 2, 2,  (n < 8 ? opw[n * 64 + k]
                        : n < 18 ? c1w[(n - 8) * 64 + k]
                        : n < 28 ? c2w[(n - 18) * 64 + k] : 0.f))
  BUILD(F_PK,   2, 4,  pkw[n * 64 + k])
}

// ---------------- MP block as a function (was a macro; macros can't hold #pragma) ----------------
__device__ __forceinline__ void mp_stage(
    short (*hbuf)[16][HS], short (*xbuf)[HS], float (*pbufw)[HS],
    int w1off, int w2off,
    const float* __restrict__ B1P, const float* __restrict__ B2P,
    const float* __restrict__ LGP, const float* __restrict__ LBP,
    const int* nnrow, int wv, int lane, int l15, int q)
{
  const f32x4 zf4 = {0.f, 0.f, 0.f, 0.f};
  bf16x8 w1f[4][4], w2f[2][4], am[2];
  #pragma unroll
  for (int c = 0; c < 4; c++)
    #pragma unroll
    for (int nb = 0; nb < 4; nb++) w1f[c][nb] = LDF(w1off + (c * 4 + nb) * 512);
  #pragma unroll
  for (int c = 0; c < 2; c++)
    #pragma unroll
    for (int nb = 0; nb < 4; nb++) w2f[c][nb] = LDF(w2off + (c * 4 + nb) * 512);
  am[0] = *(const bf16x8*)&xbuf[l15][q * 8];
  am[1] = *(const bf16x8*)&xbuf[l15][32 + q * 8];
  float b1v[4], b2v[4], lgv[4], lbv[4];
  #pragma unroll
  for (int nb = 0; nb < 4; nb++) {
    int cc = l15 + 16 * nb;
    b1v[nb] = B1P[cc]; b2v[nb] = B2P[cc];
    lgv[nb] = LGP[cc]; lbv[nb] = LBP[cc];
  }
  f32x4 macc[4];
  #pragma unroll
  for (int nb = 0; nb < 4; nb++) macc[nb] = zf4;
  short* tsc = (short*)&pbufw[0][0];
  for (int n = wv; n < NM; n += 4) {
    bf16x8 a0 = *(const bf16x8*)&hbuf[n][l15][q * 8];
    bf16x8 a1 = *(const bf16x8*)&hbuf[n][l15][32 + q * 8];
    f32x4 tout[4];
    #pragma unroll
    for (int nb = 0; nb < 4; nb++) {
      f32x4 acc = MFMA(a0, w1f[0][nb], zf4);
      acc = MFMA(a1, w1f[1][nb], acc);
      acc = MFMA(am[0], w1f[2][nb], acc);
      acc = MFMA(am[1], w1f[3][nb], acc);
      tout[nb] = acc;
    }
    #pragma unroll
    for (int nb = 0; nb < 4; nb++)
      #pragma unroll
      for (int i = 0; i < 4; i++)
        tsc[(q * 4 + i) * HS + l15 + 16 * nb] =
          bf16rn(fmaxf(tout[nb][i] + b1v[nb], 0.f));
    asm volatile("s_waitcnt lgkmcnt(0)" ::: "memory");
    bf16x8 t0 = *(const bf16x8*)&tsc[l15 * HS + q * 8];
    bf16x8 t1 = *(const bf16x8*)&tsc[l15 * HS + 32 + q * 8];
    f32x4 h1[4];
    #pragma unroll
    for (int nb = 0; nb < 4; nb++) {
      f32x4 acc = MFMA(t0, w2f[0][nb], zf4);
      acc = MFMA(t1, w2f[1][nb], acc);
      h1[nb] = acc;
    }
    #pragma unroll
    for (int i = 0; i < 4; i++) {
      float y[4]; float s = 0.f;
      #pragma unroll
      for (int nb = 0; nb < 4; nb++) {
        float h0v = bf2f(hbuf[n][q * 4 + i][l15 + 16 * nb]);
        y[nb] = h1[nb][i] + b2v[nb] + h0v; s += y[nb];
      }
      s += __shfl_xor(s, 1, 64); s += __shfl_xor(s, 2, 64);
      s += __shfl_xor(s, 4, 64); s += __shfl_xor(s, 8, 64);
      float mu = s * 0.015625f; float vs = 0.f;
      #pragma unroll
      for (int nb = 0; nb < 4; nb++) { y[nb] -= mu; vs += y[nb] * y[nb]; }
      vs += __shfl_xor(vs, 1, 64); vs += __shfl_xor(vs, 2, 64);
      vs += __shfl_xor(vs, 4, 64); vs += __shfl_xor(vs, 8, 64);
      float rstd = rsqrtf(vs * 0.015625f + 1e-5f);
      float mfv = (n < nnrow[i]) ? 1.f : 0.f;
      #pragma unroll
      for (int nb = 0; nb < 4; nb++) {
        float hv = (y[nb] * rstd * lgv[nb] + lbv[nb]) * mfv;
        hbuf[n][q * 4 + i][l15 + 16 * nb] = bf16rn(hv);
        macc[nb][i] += hv;
      }
    }
  }
  asm volatile("s_waitcnt lgkmcnt(0)" ::: "memory");
  #pragma unroll
  for (int nb = 0; nb < 4; nb++)
    #pragma unroll
    for (int i = 0; i < 4; i++)
      pbufw[q * 4 + i][l15 + 16 * nb] = macc[nb][i];
}

// ---------------- main fused kernel: 16 batch elems / workgroup ----------------
__global__ void __launch_bounds__(256)
msp_mfma(const float* __restrict__ nf, const int* __restrict__ nnp,
         const float* __restrict__ rnn, const float* __restrict__ poh,
         const float* __restrict__ ne_b,
         const float* __restrict__ m1b1, const float* __restrict__ m1b2,
         const float* __restrict__ n1g, const float* __restrict__ n1b,
         const float* __restrict__ m2b1, const float* __restrict__ m2b2,
         const float* __restrict__ n2g, const float* __restrict__ n2b,
         const float* __restrict__ bih, const float* __restrict__ bhh,
         const float* __restrict__ opb, const float* __restrict__ c1b,
         const float* __restrict__ c2b, const float* __restrict__ pqb,
         const float* __restrict__ pkb,
         float* __restrict__ out, int B)
{
  __shared__ __align__(16) short hbuf[NM][16][HS];   // 46080 B, h per node (bf16)
  __shared__ __align__(16) short xbuf[16][HS];       // msg / gv / ns round-trips
  __shared__ __align__(16) short qbuf[16][HS];       // pointer query
  __shared__ __align__(16) float pbuf[4][16][HS];    // per-wave partials + t-scratch
  __shared__ int   nn_sh[16];
  __shared__ float inv_sh[16];

  const int tid  = threadIdx.x;
  const int wv   = tid >> 6;
  const int lane = tid & 63;
  const int l15  = lane & 15;
  const int q    = lane >> 4;
  const int b0   = blockIdx.x * 16;

  if (tid < 16) { int v = nnp[b0 + tid]; nn_sh[tid] = v; inv_sh[tid] = 1.0f / (float)v; }
  __syncthreads();

  int nnrow[4];
  #pragma unroll
  for (int i = 0; i < 4; i++) nnrow[i] = nn_sh[q * 4 + i];

  const f32x4 zf4 = {0.f, 0.f, 0.f, 0.f};

  // ================= stage E: h0 = nf @ ne_w^T + ne_b =================
  {
    f32x4 macc[4];
    #pragma unroll
    for (int nb = 0; nb < 4; nb++) macc[nb] = zf4;
    bf16x8 nef[4]; float neb[4];
    #pragma unroll
    for (int nb = 0; nb < 4; nb++) { nef[nb] = LDF(F_NE + nb * 512); neb[nb] = ne_b[l15 + 16 * nb]; }
    for (int n = wv; n < NM; n += 4) {
      bf16x8 a;
      #pragma unroll
      for (int j = 0; j < 8; j++) a[j] = 0;
      if (q < 2) {
        const float* p = nf + ((size_t)(b0 + l15) * NM + n) * 16 + q * 8;
        #pragma unroll
        for (int j = 0; j < 8; j++) a[j] = bf16rn(p[j]);
      }
      #pragma unroll
      for (int nb = 0; nb < 4; nb++) {
        f32x4 acc = MFMA(a, nef[nb], zf4);
        #pragma unroll
        for (int i = 0; i < 4; i++) {
          float v = acc[i] + neb[nb];
          hbuf[n][q * 4 + i][l15 + 16 * nb] = bf16rn(v);   // UNMASKED h0
          if (n < nnrow[i]) macc[nb][i] += v;              // masked msg partial
        }
      }
    }
    #pragma unroll
    for (int nb = 0; nb < 4; nb++)
      #pragma unroll
      for (int i = 0; i < 4; i++)
        pbuf[wv][q * 4 + i][l15 + 16 * nb] = macc[nb][i];
  }

  #define REDUCE_TO(dst)                                                       \
    __syncthreads();                                                           \
    for (int idx = tid; idx < 1024; idx += 256) {                              \
      int r = idx >> 6, c = idx & 63;                                          \
      float s = pbuf[0][r][c] + pbuf[1][r][c] + pbuf[2][r][c] + pbuf[3][r][c]; \
      dst[r][c] = bf16rn(s * inv_sh[r]);                                       \
    }                                                                          \
    __syncthreads();

  REDUCE_TO(xbuf)   // msg1
  mp_stage(hbuf, xbuf, pbuf[wv], F_M1W1, F_M1W2, m1b1, m1b2, n1g, n1b,
           nnrow, wv, lane, l15, q);
  REDUCE_TO(xbuf)   // msg2
  mp_stage(hbuf, xbuf, pbuf[wv], F_M2W1, F_M2W2, m2b1, m2b2, n2g, n2b,
           nnrow, wv, lane, l15, q);
  REDUCE_TO(xbuf)   // graph_vec

  // ================= GRU + heads (wave 0) =================
  if (wv == 0) {
    bf16x8 ax0 = *(const bf16x8*)&xbuf[l15][q * 8];
    bf16x8 ax1 = *(const bf16x8*)&xbuf[l15][32 + q * 8];
    bf16x8 ax2;
    #pragma unroll
    for (int j = 0; j < 8; j++) ax2[j] = 0;
    if (q == 0) {
      const float* pp = poh + (size_t)(b0 + l15) * 8;
      #pragma unroll
      for (int j = 0; j < 8; j++) ax2[j] = bf16rn(pp[j]);
    }
    bf16x8 ah0, ah1;
    {
      const float* pr = rnn + (size_t)(b0 + l15) * 64;
      #pragma unroll
      for (int j = 0; j < 8; j++) { ah0[j] = bf16rn(pr[q * 8 + j]); ah1[j] = bf16rn(pr[32 + q * 8 + j]); }
    }
    f32x4 X[8], gin[4], ghn[4];
    #pragma unroll
    for (int nb = 0; nb < 12; nb++) {
      f32x4 a = MFMA(ax0, LDF(F_WIH + (0 * 12 + nb) * 512), zf4);
      a = MFMA(ax1, LDF(F_WIH + (1 * 12 + nb) * 512), a);
      a = MFMA(ax2, LDF(F_WIH + (2 * 12 + nb) * 512), a);
      f32x4 h = MFMA(ah0, LDF(F_WHH + (0 * 12 + nb) * 512), zf4);
      h = MFMA(ah1, LDF(F_WHH + (1 * 12 + nb) * 512), h);
      int col = l15 + 16 * nb;
      float bi = bih[col], bh = bhh[col];
      if (nb < 8) {
        #pragma unroll
        for (int i = 0; i < 4; i++) X[nb][i] = (a[i] + bi) + (h[i] + bh);
      } else {
        #pragma unroll
        for (int i = 0; i < 4; i++) { gin[nb - 8][i] = a[i] + bi; ghn[nb - 8][i] = h[i] + bh; }
      }
    }
    float ns[4][4];
    #pragma unroll
    for (int i = 0; i < 4; i++) {
      int b = b0 + q * 4 + i;
      #pragma unroll
      for (int nb = 0; nb < 4; nb++) {
        float r = 1.f / (1.f + expf(-X[nb][i]));
        float z = 1.f / (1.f + expf(-X[nb + 4][i]));
        float ng = tanhf(gin[nb][i] + r * ghn[nb][i]);
        float st = rnn[(size_t)b * 64 + l15 + 16 * nb];
        float v = (1.f - z) * ng + z * st;
        ns[i][nb] = v;
        out[(size_t)B * 48 + (size_t)b * 64 + (l15 + 16 * nb)] = v;
      }
    }
    // ns -> A-frag round trip
    #pragma unroll
    for (int i = 0; i < 4; i++)
      #pragma unroll
      for (int nb = 0; nb < 4; nb++)
        xbuf[q * 4 + i][l15 + 16 * nb] = bf16rn(ns[i][nb]);
    asm volatile("s_waitcnt lgkmcnt(0)" ::: "memory");
    bf16x8 an0 = *(const bf16x8*)&xbuf[l15][q * 8];
    bf16x8 an1 = *(const bf16x8*)&xbuf[l15][32 + q * 8];
    // op/c1/c2 packed head
    #pragma unroll
    for (int nb = 0; nb < 2; nb++) {
      f32x4 a = MFMA(an0, LDF(F_PACK + (0 * 2 + nb) * 512), zf4);
      a = MFMA(an1, LDF(F_PACK + (1 * 2 + nb) * 512), a);
      int col = l15 + 16 * nb;
      float bias = col < 8 ? opb[col] : col < 18 ? c1b[col - 8] : col < 28 ? c2b[col - 18] : 0.f;
      #pragma unroll
      for (int i = 0; i < 4; i++) {
        int b = b0 + q * 4 + i; float v = a[i] + bias;
        if (col < 8)       out[(size_t)b * 8 + col] = v;
        else if (col < 18) out[(size_t)B * 8 + (size_t)b * 10 + (col - 8)] = v;
        else if (col < 28) out[(size_t)B * 18 + (size_t)b * 10 + (col - 18)] = v;
      }
    }
    // q = ns @ pq^T + pqb
    #pragma unroll
    for (int nb = 0; nb < 4; nb++) {
      f32x4 a = MFMA(an0, LDF(F_PQ + (0 * 4 + nb) * 512), zf4);
      a = MFMA(an1, LDF(F_PQ + (1 * 4 + nb) * 512), a);
      float bias = pqb[l15 + 16 * nb];
      #pragma unroll
      for (int i = 0; i < 4; i++)
        qbuf[q * 4 + i][l15 + 16 * nb] = bf16rn(a[i] + bias);
    }
  }
  __syncthreads();

  // ================= pointer logits =================
  {
    bf16x8 pkf[2][4];
    #pragma unroll
    for (int c = 0; c < 2; c++)
      #pragma unroll
      for (int nb = 0; nb < 4; nb++) pkf[c][nb] = LDF(F_PK + (c * 4 + nb) * 512);
    float pkbv[4], qv[4][4];
    #pragma unroll
    for (int nb = 0; nb < 4; nb++) {
      pkbv[nb] = pkb[l15 + 16 * nb];
      #pragma unroll
      for (int i = 0; i < 4; i++) qv[nb][i] = bf2f(qbuf[q * 4 + i][l15 + 16 * nb]);
    }
    for (int n = wv; n < NM; n += 4) {
      bf16x8 a0 = *(const bf16x8*)&hbuf[n][l15][q * 8];
      bf16x8 a1 = *(const bf16x8*)&hbuf[n][l15][32 + q * 8];
      f32x4 kk[4];
      #pragma unroll
      for (int nb = 0; nb < 4; nb++) {
        f32x4 acc = MFMA(a0, pkf[0][nb], zf4);
        acc = MFMA(a1, pkf[1][nb], acc);
        kk[nb] = acc;
      }
      float s[4];
      #pragma unroll
      for (int i = 0; i < 4; i++) {
        float tt = 0.f;
        #pragma unroll
        for (int nb = 0; nb < 4; nb++) tt += qv[nb][i] * (kk[nb][i] + pkbv[nb]);
        tt += __shfl_xor(tt, 1, 64); tt += __shfl_xor(tt, 2, 64);
        tt += __shfl_xor(tt, 4, 64); tt += __shfl_xor(tt, 8, 64);
        s[i] = tt;
      }
      if (l15 == 0) {
        #pragma unroll
        for (int i = 0; i < 4; i++) {
          int r = q * 4 + i; int b = b0 + r;
          out[(size_t)B * 28 + (size_t)b * 20 + n] = (n < nnrow[i]) ? s[i] : -1e9f;
        }
      }
    }
  }
}

extern "C" void kernel_launch(void* const* d_in, const int* in_sizes, int n_in,
                              void* d_out, int out_size, void* d_ws, size_t ws_size,
                              hipStream_t stream)
{
  (void)n_in; (void)out_size; (void)d_ws; (void)ws_size;
  const float* nf   = (const float*)d_in[0];
  const int*   nnp  = (const int*)  d_in[1];
  const float* rnn  = (const float*)d_in[2];
  const float* poh  = (const float*)d_in[3];
  const float* ne_w = (const float*)d_in[4];
  const float* ne_b = (const float*)d_in[5];
  const float* m1w1 = (const float*)d_in[6];
  const float* m1b1 = (const float*)d_in[7];
  const float* m1w2 = (const float*)d_in[8];
  const float* m1b2 = (const float*)d_in[9];
  const float* n1g  = (const float*)d_in[10];
  const float* n1b  = (const float*)d_in[11];
  const float* m2w1 = (const float*)d_in[12];
  const float* m2b1 = (const float*)d_in[13];
  const float* m2w2 = (const float*)d_in[14];
  const float* m2b2 = (const float*)d_in[15];
  const float* n2g  = (const float*)d_in[16];
  const float* n2b  = (const float*)d_in[17];
  const float* wih  = (const float*)d_in[18];
  const float* whh  = (const float*)d_in[19];
  const float* bih  = (const float*)d_in[20];
  const float* bhh  = (const float*)d_in[21];
  const float* opw  = (const float*)d_in[22];
  const float* opb  = (const float*)d_in[23];
  const float* c1w  = (const float*)d_in[24];
  const float* c1b  = (const float*)d_in[25];
  const float* c2w  = (const float*)d_in[26];
  const float* c2b  = (const float*)d_in[27];
  const float* pqw  = (const float*)d_in[28];
  const float* pqb  = (const float*)d_in[29];
  const float* pkw  = (const float*)d_in[30];
  const float* pkb  = (const float*)d_in[31];
  float* out = (float*)d_out;
  const int B = in_sizes[1];

  prep_frag<<<66, 256, 0, stream>>>(ne_w, m1w1, m1w2, m2w1, m2w2,
                                    wih, whh, pqw, opw, c1w, c2w, pkw);
  msp_mfma<<<B / 16, 256, 0, stream>>>(nf, nnp, rnn, poh, ne_b,
                                       m1b1, m1b2, n1g, n1b,
                                       m2b1, m2b2, n2g, n2b,
                                       bih, bhh, opb, c1b, c2b,
                                       pqb, pkb, out, B);
}